// Round 2
// 864.140 us; speedup vs baseline: 1.0139x; 1.0139x over previous
//
#include <hip/hip_runtime.h>
#include <hip/hip_bf16.h>
#include <math.h>

// B=2,H=12 -> 24 heads, S=2048, D=64, fp32 in; out = ctx[24,2048,64] ++ attn[24,2048,2048].
//
// Round 4: barrier-free in-kernel pass A (workspace-neutral rewrite of the round-3 split).
//  - Pass A: each wave sweeps kt = 4j+w reading K fragments straight from the pre-swizzled
//    global kw (same addresses as the old LDS reads) into registers: no LDS staging, no
//    per-step barriers (old pass A paid 64 __syncthreads + staging latency for 32 steps).
//    Only 2 barriers for the Z reduce; zred/zinv overlaid on the then-dead es tile.
//  - Pass B: unchanged round-2 logic + early K/V register prefetch at the TOP of each step
//    so QK+exp+stores+PV cover the global-load latency.
//  - Workspace identical to the round-2 passing kernel (qw,kw,vw only — no zpart).
//  - Numerics identical except Z's fp32 summation tree (re-association; tol ~1/536).

#define S_LEN 2048
#define DK    64
#define MQ    64
#define KSLAB 64
#define NSTEP (S_LEN / KSLAB)   // 32
#define NQB   (S_LEN / MQ)      // 32
#define DOT_EPS 0.02f

typedef __attribute__((ext_vector_type(8))) short bf16x8;
typedef __attribute__((ext_vector_type(4))) float f32x4;

__device__ inline short f2bf(float x) {
  __hip_bfloat16 b = __float2bfloat16(x);
  return *reinterpret_cast<short*>(&b);
}
__device__ inline float bf2f(short s) {
  __hip_bfloat16 b = *reinterpret_cast<__hip_bfloat16*>(&s);
  return __bfloat162float(b);
}

// exact round-1 score chain: sequential fmaf over d=0..63 (bit-identical to baseline)
__device__ float exact_dot(const float* __restrict__ Qr, const float* __restrict__ Kr) {
  float acc = 0.f;
  #pragma unroll
  for (int d4 = 0; d4 < 16; ++d4) {
    float4 a = ((const float4*)Qr)[d4];
    float4 b = ((const float4*)Kr)[d4];
    acc = fmaf(a.x, b.x, acc);
    acc = fmaf(a.y, b.y, acc);
    acc = fmaf(a.z, b.z, acc);
    acc = fmaf(a.w, b.w, acc);
  }
  return acc;
}

// ---------------- prep kernel: build bf16 planes in ws ----------------
// QW: per head [q][plane2][64]                       (plain)
// KW: per head [kt16:128][row16][plane2][blk8^ (row&7)][8]
// VW: per head [slab:32][d64][blk8 ^ (d&7)][8]       (V transposed: Vt[d][k])
__global__ __launch_bounds__(256) void prep_kernel(
    const float* __restrict__ Q, const float* __restrict__ K, const float* __restrict__ V,
    short* __restrict__ qw, short* __restrict__ kw, short* __restrict__ vw, int secblocks) {
  const int bid = blockIdx.x, tid = threadIdx.x;
  if (bid < secblocks) {               // ---- Q section ----
    int flat = bid * 256 + tid;        // (head, q, b) over heads*2048*8
    int head = flat >> 14;
    int rem = flat & 16383;
    int q = rem >> 3, b = rem & 7;
    const float* src = Q + (size_t)(head * S_LEN + q) * DK + b * 8;
    bf16x8 hv, mv;
    #pragma unroll
    for (int i = 0; i < 8; ++i) {
      float x = src[i];
      short h = f2bf(x);
      short m = f2bf(x - bf2f(h));
      hv[i] = h; mv[i] = m;
    }
    short* dst = qw + (size_t)(head * S_LEN + q) * 128;
    *(bf16x8*)(dst + 0 * 64 + b * 8) = hv;
    *(bf16x8*)(dst + 1 * 64 + b * 8) = mv;
  } else if (bid < 2 * secblocks) {    // ---- K section ----
    int flat = (bid - secblocks) * 256 + tid;   // (head, kt, row, b)
    int head = flat >> 14;
    int rem = flat & 16383;
    int kt = rem >> 7;
    int row = (rem >> 3) & 15, b = rem & 7;
    const float* src = K + (size_t)(head * S_LEN + kt * 16 + row) * DK + b * 8;
    bf16x8 hv, mv;
    #pragma unroll
    for (int i = 0; i < 8; ++i) {
      float x = src[i];
      short h = f2bf(x);
      short m = f2bf(x - bf2f(h));
      hv[i] = h; mv[i] = m;
    }
    int bs = b ^ (row & 7);
    short* dst = kw + ((size_t)(head * 128 + kt) * 16 + row) * 128;
    *(bf16x8*)(dst + 0 * 64 + bs * 8) = hv;
    *(bf16x8*)(dst + 1 * 64 + bs * 8) = mv;
  } else {                             // ---- V section (transpose) ----
    int wid = (bid - 2 * secblocks) * 4 + (tid >> 6);  // (head, slab, b) over heads*32*8
    int lane = tid & 63;               // = d
    int head = wid >> 8;
    int rem = wid & 255;
    int slab = rem >> 3, b = rem & 7;
    bf16x8 vv;
    #pragma unroll
    for (int j = 0; j < 8; ++j)
      vv[j] = f2bf(V[(size_t)(head * S_LEN + slab * 64 + b * 8 + j) * DK + lane]);
    int bs = b ^ (lane & 7);
    *(bf16x8*)(vw + ((size_t)(head * 32 + slab) * 64 + lane) * 64 + bs * 8) = vv;
  }
}

// ---------------- main kernel ----------------
__global__ __launch_bounds__(256, 2) void sdpa_mfma(
    const float* __restrict__ Q, const float* __restrict__ K,
    const short* __restrict__ qw, const short* __restrict__ kw, const short* __restrict__ vw,
    float* __restrict__ ctx_out, float* __restrict__ attn_out) {
  __shared__ short Ks[8192];        // 4 k-tiles x [row16][plane2][blk8][8]   (16 KB)
  __shared__ short Vt[2][4096];     // dbuf: [d64][blk8][8]                   (16 KB)
  __shared__ short es[4096];        // [q64][blk8 ^ (q&7)][8]  (e in bf16)    ( 8 KB)
  // zred/zinv overlaid on es: only used before es is first written (barriers separate).
  float (*zredp)[MQ] = (float(*)[MQ])es;
  float* zinvp = (float*)es + 4 * MQ;

  const int head = blockIdx.y;
  const int q0 = blockIdx.x * MQ;
  const int tid = threadIdx.x;
  const int w = tid >> 6;
  const int lane = tid & 63;
  const int l15 = lane & 15;
  const int quad = lane >> 4;

  const short* QW = qw + (size_t)head * (S_LEN * 128);
  const short* KW = kw + (size_t)head * (128 * 16 * 128);
  const short* VW = vw + (size_t)head * (32 * 4096);
  const float* Qg = Q + (size_t)head * S_LEN * DK;
  const float* Kg = K + (size_t)head * S_LEN * DK;

  const f32x4 zf = {0.f, 0.f, 0.f, 0.f};

  // Q B-operand fragments, resident in registers for the whole kernel.
  // B[k=d][n=q]: lane: n=l15 -> q = qt*16+l15 ; k = c*32 + quad*8 + j
  bf16x8 qf[2][2][4];   // [plane][chunk][qt]
  #pragma unroll
  for (int p = 0; p < 2; ++p)
    #pragma unroll
    for (int c = 0; c < 2; ++c)
      #pragma unroll
      for (int qt = 0; qt < 4; ++qt)
        qf[p][c][qt] = *(const bf16x8*)(QW + (size_t)(q0 + qt * 16 + l15) * 128 + p * 64 + (c * 4 + quad) * 8);

  // ================= pass A: Z (barrier-free; K fragments straight from global kw) =======
  // Wave w covers kt = 4j+w (identical partition to the old staged pass A).
  float zp[4] = {0.f, 0.f, 0.f, 0.f};
  #pragma unroll 2
  for (int j = 0; j < NSTEP; ++j) {
    const int kt = 4 * j + w;
    const short* kb = KW + ((size_t)kt * 16 + l15) * 128;
    bf16x8 ak[2][2];
    #pragma unroll
    for (int p = 0; p < 2; ++p)
      #pragma unroll
      for (int c = 0; c < 2; ++c)
        ak[p][c] = *(const bf16x8*)(kb + p * 64 + (((c * 4 + quad) ^ (l15 & 7)) * 8));
    f32x4 acc[4] = {zf, zf, zf, zf};
    #pragma unroll
    for (int qt = 0; qt < 4; ++qt)
      #pragma unroll
      for (int c = 0; c < 2; ++c) {
        acc[qt] = __builtin_amdgcn_mfma_f32_16x16x32_bf16(ak[0][c], qf[0][c][qt], acc[qt], 0, 0, 0);
        acc[qt] = __builtin_amdgcn_mfma_f32_16x16x32_bf16(ak[1][c], qf[0][c][qt], acc[qt], 0, 0, 0);
        acc[qt] = __builtin_amdgcn_mfma_f32_16x16x32_bf16(ak[0][c], qf[1][c][qt], acc[qt], 0, 0, 0);
      }
    #pragma unroll
    for (int qt = 0; qt < 4; ++qt)
      #pragma unroll
      for (int r = 0; r < 4; ++r) {
        float d = acc[qt][r];
        zp[qt] += (d < 0.f) ? __expf(d * 0.125f) : 0.f;
      }
  }

  // Z reduce: quads hold disjoint k -> shfl over lane bits 4,5; waves via LDS
  #pragma unroll
  for (int qt = 0; qt < 4; ++qt) {
    float v = zp[qt];
    v += __shfl_xor(v, 16);
    v += __shfl_xor(v, 32);
    if (lane < 16) zredp[w][qt * 16 + lane] = v;
  }
  __syncthreads();
  if (tid < MQ) {
    float Z = zredp[0][tid] + zredp[1][tid] + zredp[2][tid] + zredp[3][tid];
    zinvp[tid] = 1.f / (Z + 1e-8f);
  }
  __syncthreads();
  float ziq[4], zctx[4];
  #pragma unroll
  for (int qt = 0; qt < 4; ++qt) ziq[qt] = zinvp[qt * 16 + l15];
  #pragma unroll
  for (int r = 0; r < 4; ++r) zctx[r] = zinvp[16 * w + quad * 4 + r];
  __syncthreads();   // zinv consumed; es free for pass B

  // QK^T (3-term split) for this thread's wave-tile: S^T tile w (k-rows 16w..16w+15)
  #define QK_COMPUTE(acc)                                                                      \
    {                                                                                          \
      bf16x8 ak[2][2];                                                                         \
      _Pragma("unroll")                                                                        \
      for (int p = 0; p < 2; ++p)                                                              \
        _Pragma("unroll")                                                                      \
        for (int c = 0; c < 2; ++c)                                                            \
          ak[p][c] = *(const bf16x8*)&Ks[w * 2048 + l15 * 128 + p * 64 +                       \
                                         (((c * 4 + quad) ^ (l15 & 7)) * 8)];                  \
      _Pragma("unroll")                                                                        \
      for (int qt = 0; qt < 4; ++qt)                                                           \
        _Pragma("unroll")                                                                      \
        for (int c = 0; c < 2; ++c) {                                                          \
          acc[qt] = __builtin_amdgcn_mfma_f32_16x16x32_bf16(ak[0][c], qf[0][c][qt], acc[qt], 0, 0, 0); \
          acc[qt] = __builtin_amdgcn_mfma_f32_16x16x32_bf16(ak[1][c], qf[0][c][qt], acc[qt], 0, 0, 0); \
          acc[qt] = __builtin_amdgcn_mfma_f32_16x16x32_bf16(ak[0][c], qf[1][c][qt], acc[qt], 0, 0, 0); \
        }                                                                                      \
    }

  // ================= pass B: attn + PV =================
  f32x4 ctxa[4] = {zf, zf, zf, zf};   // [dt]; C rows q=16w+quad*4+reg, cols d=dt*16+l15
  {
    #pragma unroll
    for (int r = 0; r < 4; ++r)
      *(bf16x8*)&Ks[(tid + 256 * r) * 8] = *(const bf16x8*)(KW + (tid + 256 * r) * 8);
    #pragma unroll
    for (int r = 0; r < 2; ++r)
      *(bf16x8*)&Vt[0][(tid + 256 * r) * 8] = *(const bf16x8*)(VW + (tid + 256 * r) * 8);
  }
  __syncthreads();
  for (int step = 0; step < NSTEP; ++step) {
    const int cur = step & 1;

    // issue next-slab prefetch EARLY: QK + exp + stores + PV cover the latency
    bf16x8 sk[4], sv[2];
    const bool more = (step + 1 < NSTEP);
    if (more) {
      const short* s = KW + (size_t)(step + 1) * 8192;
      #pragma unroll
      for (int r = 0; r < 4; ++r) sk[r] = *(const bf16x8*)(s + (tid + 256 * r) * 8);
      const short* v = VW + (size_t)(step + 1) * 4096;
      #pragma unroll
      for (int r = 0; r < 2; ++r) sv[r] = *(const bf16x8*)(v + (tid + 256 * r) * 8);
    }

    f32x4 acc[4] = {zf, zf, zf, zf};
    QK_COMPUTE(acc);

    const int kbase = step * 64 + 16 * w + quad * 4;
    #pragma unroll
    for (int qt = 0; qt < 4; ++qt) {
      float e4[4];
      #pragma unroll
      for (int r = 0; r < 4; ++r) {
        float d = acc[qt][r];
        if (fabsf(d) < DOT_EPS) {   // rare (~0.2%): exact sign via round-1 chain
          d = exact_dot(Qg + (size_t)(q0 + qt * 16 + l15) * DK,
                        Kg + (size_t)(kbase + r) * DK);
        }
        e4[r] = (d < 0.f) ? __expf(d * 0.125f) : 0.f;
      }
      float4 av = {e4[0] * ziq[qt], e4[1] * ziq[qt], e4[2] * ziq[qt], e4[3] * ziq[qt]};
      *(float4*)(attn_out + (size_t)(head * S_LEN + q0 + qt * 16 + l15) * S_LEN + kbase) = av;
      // es write: row q=qt*16+l15, k-offset 16w+quad*4 (+r), 16B-block swizzle ^ (q&7)
      int qe = qt * 16 + l15;
      int blk = 2 * w + (quad >> 1);
      short* ep = &es[qe * 64 + ((blk ^ (qe & 7)) * 8) + (quad & 1) * 4];
      *(short4*)ep = make_short4(f2bf(e4[0]), f2bf(e4[1]), f2bf(e4[2]), f2bf(e4[3]));
    }
    __syncthreads();   // es complete; Ks consumed by QK

    // PV: wave w owns q-tile w. A = es (A[m=q][k]), B = Vt (B[k][n=d])
    {
      bf16x8 ea[2];
      const int qe = 16 * w + l15;
      #pragma unroll
      for (int c = 0; c < 2; ++c)
        ea[c] = *(const bf16x8*)&es[qe * 64 + (((c * 4 + quad) ^ (l15 & 7)) * 8)];
      #pragma unroll
      for (int dt = 0; dt < 4; ++dt) {
        const int de = dt * 16 + l15;
        #pragma unroll
        for (int c = 0; c < 2; ++c) {
          bf16x8 vb = *(const bf16x8*)&Vt[cur][de * 64 + (((c * 4 + quad) ^ (l15 & 7)) * 8)];
          ctxa[dt] = __builtin_amdgcn_mfma_f32_16x16x32_bf16(ea[c], vb, ctxa[dt], 0, 0, 0);
        }
      }
    }
    if (more) {
      #pragma unroll
      for (int r = 0; r < 4; ++r) *(bf16x8*)&Ks[(tid + 256 * r) * 8] = sk[r];
      #pragma unroll
      for (int r = 0; r < 2; ++r) *(bf16x8*)&Vt[cur ^ 1][(tid + 256 * r) * 8] = sv[r];
    }
    __syncthreads();   // staging + PV complete
  }

  // ctx store
  #pragma unroll
  for (int dt = 0; dt < 4; ++dt)
    #pragma unroll
    for (int r = 0; r < 4; ++r) {
      int q = 16 * w + quad * 4 + r;
      ctx_out[(size_t)(head * S_LEN + q0 + q) * DK + dt * 16 + l15] = ctxa[dt][r] * zctx[r];
    }
}

extern "C" void kernel_launch(void* const* d_in, const int* in_sizes, int n_in,
                              void* d_out, int out_size, void* d_ws, size_t ws_size,
                              hipStream_t stream) {
  const float* Q = (const float*)d_in[0];
  const float* K = (const float*)d_in[1];
  const float* V = (const float*)d_in[2];
  const int heads = in_sizes[0] / (S_LEN * DK);   // 24

  float* ctx = (float*)d_out;
  float* attn = (float*)d_out + (size_t)heads * S_LEN * DK;

  short* qw = (short*)d_ws;                                  // heads*2048*128 bf16
  short* kw = qw + (size_t)heads * S_LEN * 128;              // heads*128*16*128
  short* vw = kw + (size_t)heads * 128 * 16 * 128;           // heads*32*4096

  const int secblocks = heads * 64;                          // blocks per prep section
  prep_kernel<<<dim3(3 * secblocks), dim3(256), 0, stream>>>(Q, K, V, qw, kw, vw, secblocks);
  sdpa_mfma<<<dim3(NQB, heads), dim3(256), 0, stream>>>(Q, K, qw, kw, vw, ctx, attn);
}

// Round 3
// 782.349 us; speedup vs baseline: 1.1199x; 1.1045x over previous
//
#include <hip/hip_runtime.h>
#include <hip/hip_bf16.h>
#include <math.h>

// B=2,H=12 -> 24 heads, S=2048, D=64, fp32 in; out = ctx[24,2048,64] ++ attn[24,2048,2048].
//
// Round 5: FULLY barrier-free main kernel (zero __syncthreads).
//  Diagnosis: round-2 showed pass B ~ 490us of the 500us: the per-step __syncthreads
//  (s_waitcnt vmcnt(0)) drains attn-store acks every step, lockstepping all waves.
//  Restructure: each wave is self-contained (owns q=16w+l15, sweeps all 64 k/step):
//   - QK: A = K tiles direct from pre-swizzled global kw (L1/L2-hot), B = own Q frags.
//     Identical MFMA chain order -> e bit-identical to the passing round-2 kernel.
//   - Z: thread's 16 S-values share q=l15 -> local sum + 2 shfl_xor. No LDS, no barrier.
//   - PV: ctx^T = V^T * e^T. A = V^T direct from global vw (already transposed+swizzled),
//     B = e^T via per-wave 2KB LDS tile (wave-synchronous ds ops only). Same products in
//     the same k-slots -> ctx bit-identical.
//   - attn stores nontemporal, fire-and-forget; no vmcnt(0) drains anywhere in the loop.
//  LDS 40960 -> 8192 B. Workspace identical to round-0.

#define S_LEN 2048
#define DK    64
#define MQ    64
#define NSTEP (S_LEN / 64)      // 32 k-slabs of 64
#define NQB   (S_LEN / MQ)      // 32
#define DOT_EPS 0.02f

typedef __attribute__((ext_vector_type(8))) short bf16x8;
typedef __attribute__((ext_vector_type(4))) float f32x4;

__device__ inline short f2bf(float x) {
  __hip_bfloat16 b = __float2bfloat16(x);
  return *reinterpret_cast<short*>(&b);
}
__device__ inline float bf2f(short s) {
  __hip_bfloat16 b = *reinterpret_cast<__hip_bfloat16*>(&s);
  return __bfloat162float(b);
}

// exact round-1 score chain: sequential fmaf over d=0..63 (bit-identical to baseline)
__device__ float exact_dot(const float* __restrict__ Qr, const float* __restrict__ Kr) {
  float acc = 0.f;
  #pragma unroll
  for (int d4 = 0; d4 < 16; ++d4) {
    float4 a = ((const float4*)Qr)[d4];
    float4 b = ((const float4*)Kr)[d4];
    acc = fmaf(a.x, b.x, acc);
    acc = fmaf(a.y, b.y, acc);
    acc = fmaf(a.z, b.z, acc);
    acc = fmaf(a.w, b.w, acc);
  }
  return acc;
}

// ---------------- prep kernel: build bf16 planes in ws ----------------
// QW: per head [q][plane2][64]                       (plain)
// KW: per head [kt16:128][row16][plane2][blk8^ (row&7)][8]
// VW: per head [slab:32][d64][blk8 ^ (d&7)][8]       (V transposed: Vt[d][k])
__global__ __launch_bounds__(256) void prep_kernel(
    const float* __restrict__ Q, const float* __restrict__ K, const float* __restrict__ V,
    short* __restrict__ qw, short* __restrict__ kw, short* __restrict__ vw, int secblocks) {
  const int bid = blockIdx.x, tid = threadIdx.x;
  if (bid < secblocks) {               // ---- Q section ----
    int flat = bid * 256 + tid;        // (head, q, b) over heads*2048*8
    int head = flat >> 14;
    int rem = flat & 16383;
    int q = rem >> 3, b = rem & 7;
    const float* src = Q + (size_t)(head * S_LEN + q) * DK + b * 8;
    bf16x8 hv, mv;
    #pragma unroll
    for (int i = 0; i < 8; ++i) {
      float x = src[i];
      short h = f2bf(x);
      short m = f2bf(x - bf2f(h));
      hv[i] = h; mv[i] = m;
    }
    short* dst = qw + (size_t)(head * S_LEN + q) * 128;
    *(bf16x8*)(dst + 0 * 64 + b * 8) = hv;
    *(bf16x8*)(dst + 1 * 64 + b * 8) = mv;
  } else if (bid < 2 * secblocks) {    // ---- K section ----
    int flat = (bid - secblocks) * 256 + tid;   // (head, kt, row, b)
    int head = flat >> 14;
    int rem = flat & 16383;
    int kt = rem >> 7;
    int row = (rem >> 3) & 15, b = rem & 7;
    const float* src = K + (size_t)(head * S_LEN + kt * 16 + row) * DK + b * 8;
    bf16x8 hv, mv;
    #pragma unroll
    for (int i = 0; i < 8; ++i) {
      float x = src[i];
      short h = f2bf(x);
      short m = f2bf(x - bf2f(h));
      hv[i] = h; mv[i] = m;
    }
    int bs = b ^ (row & 7);
    short* dst = kw + ((size_t)(head * 128 + kt) * 16 + row) * 128;
    *(bf16x8*)(dst + 0 * 64 + bs * 8) = hv;
    *(bf16x8*)(dst + 1 * 64 + bs * 8) = mv;
  } else {                             // ---- V section (transpose) ----
    int wid = (bid - 2 * secblocks) * 4 + (tid >> 6);  // (head, slab, b) over heads*32*8
    int lane = tid & 63;               // = d
    int head = wid >> 8;
    int rem = wid & 255;
    int slab = rem >> 3, b = rem & 7;
    bf16x8 vv;
    #pragma unroll
    for (int j = 0; j < 8; ++j)
      vv[j] = f2bf(V[(size_t)(head * S_LEN + slab * 64 + b * 8 + j) * DK + lane]);
    int bs = b ^ (lane & 7);
    *(bf16x8*)(vw + ((size_t)(head * 32 + slab) * 64 + lane) * 64 + bs * 8) = vv;
  }
}

// ---------------- main kernel: zero-barrier, per-wave independent ----------------
__global__ __launch_bounds__(256, 3) void sdpa_mfma(
    const float* __restrict__ Q, const float* __restrict__ K,
    const short* __restrict__ qw, const short* __restrict__ kw, const short* __restrict__ vw,
    float* __restrict__ ctx_out, float* __restrict__ attn_out) {
  __shared__ short es[4][1024];     // per-wave [q16][k64] bf16, 16B-block swizzle ^ (q&7)

  const int head = blockIdx.y;
  const int q0 = blockIdx.x * MQ;
  const int tid = threadIdx.x;
  const int w = tid >> 6;
  const int lane = tid & 63;
  const int l15 = lane & 15;
  const int quad = lane >> 4;
  const int qrow = q0 + 16 * w + l15;    // this thread's q row (fixed for whole kernel)

  const short* QW = qw + (size_t)head * (S_LEN * 128);
  const short* KW = kw + (size_t)head * (128 * 16 * 128);
  const short* VW = vw + (size_t)head * (32 * 4096);
  const float* Qg = Q + (size_t)head * S_LEN * DK;
  const float* Kg = K + (size_t)head * S_LEN * DK;

  const f32x4 zf = {0.f, 0.f, 0.f, 0.f};

  // Q B-operand fragments for THIS wave's q-tile only. B[k=d][n=q]: n=l15 -> q = qrow;
  // k = c*32 + quad*8 + j.
  bf16x8 qf[2][2];   // [plane][chunk]
  #pragma unroll
  for (int p = 0; p < 2; ++p)
    #pragma unroll
    for (int c = 0; c < 2; ++c)
      qf[p][c] = *(const bf16x8*)(QW + (size_t)qrow * 128 + p * 64 + (c * 4 + quad) * 8);

  // QK for one 64k x 16q slab: acc[kt]; C[m=k][n=q]: col=l15=q, row=quad*4+r = k-in-tile.
  // Same 6-MFMA chain order as the passing kernel -> bit-identical dots.
  #define QK_SLAB(acc, slabBase)                                                               \
    {                                                                                          \
      _Pragma("unroll")                                                                        \
      for (int kt = 0; kt < 4; ++kt) {                                                         \
        const short* kb = (slabBase) + ((size_t)kt * 16 + l15) * 128;                          \
        bf16x8 ak[2][2];                                                                       \
        _Pragma("unroll")                                                                      \
        for (int p = 0; p < 2; ++p)                                                            \
          _Pragma("unroll")                                                                    \
          for (int c = 0; c < 2; ++c)                                                          \
            ak[p][c] = *(const bf16x8*)(kb + p * 64 + (((c * 4 + quad) ^ (l15 & 7)) * 8));     \
        _Pragma("unroll")                                                                      \
        for (int c = 0; c < 2; ++c) {                                                          \
          acc[kt] = __builtin_amdgcn_mfma_f32_16x16x32_bf16(ak[0][c], qf[0][c], acc[kt], 0, 0, 0); \
          acc[kt] = __builtin_amdgcn_mfma_f32_16x16x32_bf16(ak[1][c], qf[0][c], acc[kt], 0, 0, 0); \
          acc[kt] = __builtin_amdgcn_mfma_f32_16x16x32_bf16(ak[0][c], qf[1][c], acc[kt], 0, 0, 0); \
        }                                                                                      \
      }                                                                                        \
    }

  // ================= pass A: Z (no LDS, no barriers) =================
  float zsum = 0.f;
  for (int step = 0; step < NSTEP; ++step) {
    const short* sb = KW + (size_t)step * 8192;
    f32x4 acc[4] = {zf, zf, zf, zf};
    QK_SLAB(acc, sb);
    #pragma unroll
    for (int kt = 0; kt < 4; ++kt)
      #pragma unroll
      for (int r = 0; r < 4; ++r) {
        float d = acc[kt][r];
        zsum += (d < 0.f) ? __expf(d * 0.125f) : 0.f;
      }
  }
  // quads hold disjoint k for the same q=l15 -> butterfly over lane bits 4,5
  zsum += __shfl_xor(zsum, 16);
  zsum += __shfl_xor(zsum, 32);
  const float zinv = 1.f / (zsum + 1e-8f);

  // ================= pass B: attn + PV (no barriers) =================
  f32x4 ctxa[4] = {zf, zf, zf, zf};   // ctx^T: [dt]; row d=dt*16+quad*4+r, col q=qrow
  short* esw = &es[w][0];             // this wave's private tile

  for (int step = 0; step < NSTEP; ++step) {
    const short* sb = KW + (size_t)step * 8192;
    f32x4 acc[4] = {zf, zf, zf, zf};
    QK_SLAB(acc, sb);

    #pragma unroll
    for (int kt = 0; kt < 4; ++kt) {
      const int kbase = step * 64 + kt * 16 + quad * 4;
      float e4[4];
      #pragma unroll
      for (int r = 0; r < 4; ++r) {
        float d = acc[kt][r];
        if (fabsf(d) < DOT_EPS) {   // rare (~0.2%): exact sign via round-1 chain
          d = exact_dot(Qg + (size_t)qrow * DK, Kg + (size_t)(kbase + r) * DK);
        }
        e4[r] = (d < 0.f) ? __expf(d * 0.125f) : 0.f;
      }
      f32x4 av = {e4[0] * zinv, e4[1] * zinv, e4[2] * zinv, e4[3] * zinv};
      __builtin_nontemporal_store(av,
          (f32x4*)(attn_out + (size_t)(head * S_LEN + qrow) * S_LEN + kbase));
      // es write: row q=l15, cols kt*16+quad*4 .. +3; block b = kt*2+(quad>>1), swz ^ (q&7)
      int b = kt * 2 + (quad >> 1);
      short* ep = esw + l15 * 64 + ((b ^ (l15 & 7)) * 8) + (quad & 1) * 4;
      *(short4*)ep = make_short4(f2bf(e4[0]), f2bf(e4[1]), f2bf(e4[2]), f2bf(e4[3]));
    }

    // PV: ctx^T += V^T * e^T. Wave-synchronous LDS (ds in-order per wave; compiler
    // inserts the lgkmcnt wait for the es read data).
    bf16x8 eb[2];
    #pragma unroll
    for (int c = 0; c < 2; ++c)
      eb[c] = *(const bf16x8*)(esw + l15 * 64 + (((c * 4 + quad) ^ (l15 & 7)) * 8));
    #pragma unroll
    for (int dt = 0; dt < 4; ++dt) {
      const int d = dt * 16 + l15;   // A[m=d][k]
      #pragma unroll
      for (int c = 0; c < 2; ++c) {
        bf16x8 va = *(const bf16x8*)(VW + (size_t)step * 4096 + (size_t)d * 64 +
                                     (((c * 4 + quad) ^ (l15 & 7)) * 8));
        ctxa[dt] = __builtin_amdgcn_mfma_f32_16x16x32_bf16(va, eb[c], ctxa[dt], 0, 0, 0);
      }
    }
  }

  // ctx store: thread holds ctx^T[d=dt*16+quad*4+r][q=qrow]; all 16 values share q -> zinv.
  #pragma unroll
  for (int dt = 0; dt < 4; ++dt) {
    float4 cv = {ctxa[dt][0] * zinv, ctxa[dt][1] * zinv, ctxa[dt][2] * zinv, ctxa[dt][3] * zinv};
    *(float4*)(ctx_out + (size_t)(head * S_LEN + qrow) * DK + dt * 16 + quad * 4) = cv;
  }
}

extern "C" void kernel_launch(void* const* d_in, const int* in_sizes, int n_in,
                              void* d_out, int out_size, void* d_ws, size_t ws_size,
                              hipStream_t stream) {
  const float* Q = (const float*)d_in[0];
  const float* K = (const float*)d_in[1];
  const float* V = (const float*)d_in[2];
  const int heads = in_sizes[0] / (S_LEN * DK);   // 24

  float* ctx = (float*)d_out;
  float* attn = (float*)d_out + (size_t)heads * S_LEN * DK;

  short* qw = (short*)d_ws;                                  // heads*2048*128 bf16
  short* kw = qw + (size_t)heads * S_LEN * 128;              // heads*128*16*128
  short* vw = kw + (size_t)heads * 128 * 16 * 128;           // heads*32*4096

  const int secblocks = heads * 64;                          // blocks per prep section
  prep_kernel<<<dim3(3 * secblocks), dim3(256), 0, stream>>>(Q, K, V, qw, kw, vw, secblocks);
  sdpa_mfma<<<dim3(NQB, heads), dim3(256), 0, stream>>>(Q, K, qw, kw, vw, ctx, attn);
}

// Round 4
// 738.297 us; speedup vs baseline: 1.1867x; 1.0597x over previous
//
#include <hip/hip_runtime.h>
#include <hip/hip_bf16.h>
#include <math.h>

// B=2,H=12 -> 24 heads, S=2048, D=64, fp32 in; out = ctx[24,2048,64] ++ attn[24,2048,2048].
//
// Round 6: zero-barrier structure (round-5) + FULL-CACHELINE attn stores.
//  Diagnosis: rounds 2-5 all satisfy dur ~= WRITE_SIZE / ~1 TB/s. The attn store pattern
//  (16 scattered 64B segments per instr, rows 8KB apart, NT) runs HBM writes at ~1/5 of
//  achievable; vmcnt FIFO couples next-step loads to slow store retirement -> all pipes idle.
//  Fix: per wave, bounce the 16q x 64k f32 attn tile through a private 4KB LDS region
//  (XOR-swizzled, ~2-way banks) and emit 4 NT store instrs of 4 rows x 256B CONTIGUOUS
//  (full 128B lines only). Same values, same compute order -> bit-identical output.
//  LDS 8KB -> 24KB (still 3 blocks/CU, VGPR 64).

#define S_LEN 2048
#define DK    64
#define MQ    64
#define NSTEP (S_LEN / 64)      // 32 k-slabs of 64
#define NQB   (S_LEN / MQ)      // 32
#define DOT_EPS 0.02f

typedef __attribute__((ext_vector_type(8))) short bf16x8;
typedef __attribute__((ext_vector_type(4))) float f32x4;

__device__ inline short f2bf(float x) {
  __hip_bfloat16 b = __float2bfloat16(x);
  return *reinterpret_cast<short*>(&b);
}
__device__ inline float bf2f(short s) {
  __hip_bfloat16 b = *reinterpret_cast<__hip_bfloat16*>(&s);
  return __bfloat162float(b);
}

// exact round-1 score chain: sequential fmaf over d=0..63 (bit-identical to baseline)
__device__ float exact_dot(const float* __restrict__ Qr, const float* __restrict__ Kr) {
  float acc = 0.f;
  #pragma unroll
  for (int d4 = 0; d4 < 16; ++d4) {
    float4 a = ((const float4*)Qr)[d4];
    float4 b = ((const float4*)Kr)[d4];
    acc = fmaf(a.x, b.x, acc);
    acc = fmaf(a.y, b.y, acc);
    acc = fmaf(a.z, b.z, acc);
    acc = fmaf(a.w, b.w, acc);
  }
  return acc;
}

// ---------------- prep kernel: build bf16 planes in ws ----------------
// QW: per head [q][plane2][64]                       (plain)
// KW: per head [kt16:128][row16][plane2][blk8^ (row&7)][8]
// VW: per head [slab:32][d64][blk8 ^ (d&7)][8]       (V transposed: Vt[d][k])
__global__ __launch_bounds__(256) void prep_kernel(
    const float* __restrict__ Q, const float* __restrict__ K, const float* __restrict__ V,
    short* __restrict__ qw, short* __restrict__ kw, short* __restrict__ vw, int secblocks) {
  const int bid = blockIdx.x, tid = threadIdx.x;
  if (bid < secblocks) {               // ---- Q section ----
    int flat = bid * 256 + tid;        // (head, q, b) over heads*2048*8
    int head = flat >> 14;
    int rem = flat & 16383;
    int q = rem >> 3, b = rem & 7;
    const float* src = Q + (size_t)(head * S_LEN + q) * DK + b * 8;
    bf16x8 hv, mv;
    #pragma unroll
    for (int i = 0; i < 8; ++i) {
      float x = src[i];
      short h = f2bf(x);
      short m = f2bf(x - bf2f(h));
      hv[i] = h; mv[i] = m;
    }
    short* dst = qw + (size_t)(head * S_LEN + q) * 128;
    *(bf16x8*)(dst + 0 * 64 + b * 8) = hv;
    *(bf16x8*)(dst + 1 * 64 + b * 8) = mv;
  } else if (bid < 2 * secblocks) {    // ---- K section ----
    int flat = (bid - secblocks) * 256 + tid;   // (head, kt, row, b)
    int head = flat >> 14;
    int rem = flat & 16383;
    int kt = rem >> 7;
    int row = (rem >> 3) & 15, b = rem & 7;
    const float* src = K + (size_t)(head * S_LEN + kt * 16 + row) * DK + b * 8;
    bf16x8 hv, mv;
    #pragma unroll
    for (int i = 0; i < 8; ++i) {
      float x = src[i];
      short h = f2bf(x);
      short m = f2bf(x - bf2f(h));
      hv[i] = h; mv[i] = m;
    }
    int bs = b ^ (row & 7);
    short* dst = kw + ((size_t)(head * 128 + kt) * 16 + row) * 128;
    *(bf16x8*)(dst + 0 * 64 + bs * 8) = hv;
    *(bf16x8*)(dst + 1 * 64 + bs * 8) = mv;
  } else {                             // ---- V section (transpose) ----
    int wid = (bid - 2 * secblocks) * 4 + (tid >> 6);  // (head, slab, b) over heads*32*8
    int lane = tid & 63;               // = d
    int head = wid >> 8;
    int rem = wid & 255;
    int slab = rem >> 3, b = rem & 7;
    bf16x8 vv;
    #pragma unroll
    for (int j = 0; j < 8; ++j)
      vv[j] = f2bf(V[(size_t)(head * S_LEN + slab * 64 + b * 8 + j) * DK + lane]);
    int bs = b ^ (lane & 7);
    *(bf16x8*)(vw + ((size_t)(head * 32 + slab) * 64 + lane) * 64 + bs * 8) = vv;
  }
}

// ---------------- main kernel: zero-barrier, per-wave independent ----------------
__global__ __launch_bounds__(256, 3) void sdpa_mfma(
    const float* __restrict__ Q, const float* __restrict__ K,
    const short* __restrict__ qw, const short* __restrict__ kw, const short* __restrict__ vw,
    float* __restrict__ ctx_out, float* __restrict__ attn_out) {
  __shared__ short es[4][1024];     // per-wave [q16][k64] bf16, 16B-block swizzle ^ (q&7)
  __shared__ float att[4][1024];    // per-wave 4KB f32 attn bounce: [row16][blk16 ^ row][4]

  const int head = blockIdx.y;
  const int q0 = blockIdx.x * MQ;
  const int tid = threadIdx.x;
  const int w = tid >> 6;
  const int lane = tid & 63;
  const int l15 = lane & 15;
  const int quad = lane >> 4;
  const int qrow = q0 + 16 * w + l15;    // this thread's q row (fixed for whole kernel)

  const short* QW = qw + (size_t)head * (S_LEN * 128);
  const short* KW = kw + (size_t)head * (128 * 16 * 128);
  const short* VW = vw + (size_t)head * (32 * 4096);
  const float* Qg = Q + (size_t)head * S_LEN * DK;
  const float* Kg = K + (size_t)head * S_LEN * DK;

  const f32x4 zf = {0.f, 0.f, 0.f, 0.f};

  // Q B-operand fragments for THIS wave's q-tile only. B[k=d][n=q]: n=l15 -> q = qrow;
  // k = c*32 + quad*8 + j.
  bf16x8 qf[2][2];   // [plane][chunk]
  #pragma unroll
  for (int p = 0; p < 2; ++p)
    #pragma unroll
    for (int c = 0; c < 2; ++c)
      qf[p][c] = *(const bf16x8*)(QW + (size_t)qrow * 128 + p * 64 + (c * 4 + quad) * 8);

  // QK for one 64k x 16q slab: acc[kt]; C[m=k][n=q]: col=l15=q, row=quad*4+r = k-in-tile.
  // Same 6-MFMA chain order as the passing kernel -> bit-identical dots.
  #define QK_SLAB(acc, slabBase)                                                               \
    {                                                                                          \
      _Pragma("unroll")                                                                        \
      for (int kt = 0; kt < 4; ++kt) {                                                         \
        const short* kb = (slabBase) + ((size_t)kt * 16 + l15) * 128;                          \
        bf16x8 ak[2][2];                                                                       \
        _Pragma("unroll")                                                                      \
        for (int p = 0; p < 2; ++p)                                                            \
          _Pragma("unroll")                                                                    \
          for (int c = 0; c < 2; ++c)                                                          \
            ak[p][c] = *(const bf16x8*)(kb + p * 64 + (((c * 4 + quad) ^ (l15 & 7)) * 8));     \
        _Pragma("unroll")                                                                      \
        for (int c = 0; c < 2; ++c) {                                                          \
          acc[kt] = __builtin_amdgcn_mfma_f32_16x16x32_bf16(ak[0][c], qf[0][c], acc[kt], 0, 0, 0); \
          acc[kt] = __builtin_amdgcn_mfma_f32_16x16x32_bf16(ak[1][c], qf[0][c], acc[kt], 0, 0, 0); \
          acc[kt] = __builtin_amdgcn_mfma_f32_16x16x32_bf16(ak[0][c], qf[1][c], acc[kt], 0, 0, 0); \
        }                                                                                      \
      }                                                                                        \
    }

  // ================= pass A: Z (no LDS, no barriers) =================
  float zsum = 0.f;
  for (int step = 0; step < NSTEP; ++step) {
    const short* sb = KW + (size_t)step * 8192;
    f32x4 acc[4] = {zf, zf, zf, zf};
    QK_SLAB(acc, sb);
    #pragma unroll
    for (int kt = 0; kt < 4; ++kt)
      #pragma unroll
      for (int r = 0; r < 4; ++r) {
        float d = acc[kt][r];
        zsum += (d < 0.f) ? __expf(d * 0.125f) : 0.f;
      }
  }
  // quads hold disjoint k for the same q=l15 -> butterfly over lane bits 4,5
  zsum += __shfl_xor(zsum, 16);
  zsum += __shfl_xor(zsum, 32);
  const float zinv = 1.f / (zsum + 1e-8f);

  // ================= pass B: attn + PV (no barriers) =================
  f32x4 ctxa[4] = {zf, zf, zf, zf};   // ctx^T: [dt]; row d=dt*16+quad*4+r, col q=qrow
  short* esw = &es[w][0];             // this wave's private e tile (bf16)
  float* aw = &att[w][0];             // this wave's private attn bounce tile (f32)

  for (int step = 0; step < NSTEP; ++step) {
    const short* sb = KW + (size_t)step * 8192;
    f32x4 acc[4] = {zf, zf, zf, zf};
    QK_SLAB(acc, sb);

    #pragma unroll
    for (int kt = 0; kt < 4; ++kt) {
      const int kbase = step * 64 + kt * 16 + quad * 4;
      float e4[4];
      #pragma unroll
      for (int r = 0; r < 4; ++r) {
        float d = acc[kt][r];
        if (fabsf(d) < DOT_EPS) {   // rare (~0.2%): exact sign via round-1 chain
          d = exact_dot(Qg + (size_t)qrow * DK, Kg + (size_t)(kbase + r) * DK);
        }
        e4[r] = (d < 0.f) ? __expf(d * 0.125f) : 0.f;
      }
      // attn bounce write: row q=l15, 16B-block b = kt*4+quad, swizzled position b^l15.
      f32x4 av = {e4[0] * zinv, e4[1] * zinv, e4[2] * zinv, e4[3] * zinv};
      *(f32x4*)(aw + l15 * 64 + ((kt * 4 + quad) ^ l15) * 4) = av;
      // es write: row q=l15, cols kt*16+quad*4 .. +3; block b = kt*2+(quad>>1), swz ^ (q&7)
      int b = kt * 2 + (quad >> 1);
      short* ep = esw + l15 * 64 + ((b ^ (l15 & 7)) * 8) + (quad & 1) * 4;
      *(short4*)ep = make_short4(f2bf(e4[0]), f2bf(e4[1]), f2bf(e4[2]), f2bf(e4[3]));
    }

    // attn store: 4 instrs, each 4 rows x 256B CONTIGUOUS (full 128B lines only).
    // lane l -> row r = 4i + (l>>4), col-block l&15 (read swizzled position (l&15)^r).
    #pragma unroll
    for (int i = 0; i < 4; ++i) {
      const int r = 4 * i + quad;
      f32x4 rv = *(const f32x4*)(aw + r * 64 + (l15 ^ r) * 4);
      __builtin_nontemporal_store(rv,
          (f32x4*)(attn_out + (size_t)(head * S_LEN + q0 + 16 * w + r) * S_LEN +
                   step * 64 + l15 * 4));
    }

    // PV: ctx^T += V^T * e^T. Wave-synchronous LDS (ds in-order per wave; compiler
    // inserts the lgkmcnt wait for the es read data).
    bf16x8 eb[2];
    #pragma unroll
    for (int c = 0; c < 2; ++c)
      eb[c] = *(const bf16x8*)(esw + l15 * 64 + (((c * 4 + quad) ^ (l15 & 7)) * 8));
    #pragma unroll
    for (int dt = 0; dt < 4; ++dt) {
      const int d = dt * 16 + l15;   // A[m=d][k]
      #pragma unroll
      for (int c = 0; c < 2; ++c) {
        bf16x8 va = *(const bf16x8*)(VW + (size_t)step * 4096 + (size_t)d * 64 +
                                     (((c * 4 + quad) ^ (l15 & 7)) * 8));
        ctxa[dt] = __builtin_amdgcn_mfma_f32_16x16x32_bf16(va, eb[c], ctxa[dt], 0, 0, 0);
      }
    }
  }

  // ctx store: thread holds ctx^T[d=dt*16+quad*4+r][q=qrow]; all 16 values share q -> zinv.
  #pragma unroll
  for (int dt = 0; dt < 4; ++dt) {
    float4 cv = {ctxa[dt][0] * zinv, ctxa[dt][1] * zinv, ctxa[dt][2] * zinv, ctxa[dt][3] * zinv};
    *(float4*)(ctx_out + (size_t)(head * S_LEN + qrow) * DK + dt * 16 + quad * 4) = cv;
  }
}

extern "C" void kernel_launch(void* const* d_in, const int* in_sizes, int n_in,
                              void* d_out, int out_size, void* d_ws, size_t ws_size,
                              hipStream_t stream) {
  const float* Q = (const float*)d_in[0];
  const float* K = (const float*)d_in[1];
  const float* V = (const float*)d_in[2];
  const int heads = in_sizes[0] / (S_LEN * DK);   // 24

  float* ctx = (float*)d_out;
  float* attn = (float*)d_out + (size_t)heads * S_LEN * DK;

  short* qw = (short*)d_ws;                                  // heads*2048*128 bf16
  short* kw = qw + (size_t)heads * S_LEN * 128;              // heads*128*16*128
  short* vw = kw + (size_t)heads * 128 * 16 * 128;           // heads*32*4096

  const int secblocks = heads * 64;                          // blocks per prep section
  prep_kernel<<<dim3(3 * secblocks), dim3(256), 0, stream>>>(Q, K, V, qw, kw, vw, secblocks);
  sdpa_mfma<<<dim3(NQB, heads), dim3(256), 0, stream>>>(Q, K, qw, kw, vw, ctx, attn);
}

// Round 5
// 662.867 us; speedup vs baseline: 1.3217x; 1.1138x over previous
//
#include <hip/hip_runtime.h>
#include <hip/hip_bf16.h>
#include <math.h>

// B=2,H=12 -> 24 heads, S=2048, D=64, fp32 in; out = ctx[24,2048,64] ++ attn[24,2048,2048].
//
// Round 7: round-6 zero-barrier structure + locality fixes.
//  Diagnosis (round-6 counters): latency-chain-bound at 3 waves/SIMD (grid-capped).
//  FETCH 250MB vs 36MB distinct -> kw/vw L2-thrashed: default round-robin block->XCD puts
//  all 24 heads on every XCD (19MB > 4MB L2).
//  Fixes (all value-preserving, output bit-identical):
//   - XCD-aware 1D grid: b = (head%8) + 8*(qb + 32*(head/8)) -> one head's 32 q-blocks on
//     one XCD; per-XCD working set 3 heads x 790KB = 2.4MB < 4MB L2.
//   - Q fp32 block-tile staged in LDS (16KB): exact_dot's Q reads become LDS (~120cy vs
//     ~700cy cold global). Occupancy is grid-capped, so the LDS is free.
//   - #pragma unroll 2 on both sweeps (VGPR headroom free at 3 blocks/CU).

#define S_LEN 2048
#define DK    64
#define MQ    64
#define NSTEP (S_LEN / 64)      // 32 k-slabs of 64
#define NQB   (S_LEN / MQ)      // 32
#define DOT_EPS 0.02f

typedef __attribute__((ext_vector_type(8))) short bf16x8;
typedef __attribute__((ext_vector_type(4))) float f32x4;

__device__ inline short f2bf(float x) {
  __hip_bfloat16 b = __float2bfloat16(x);
  return *reinterpret_cast<short*>(&b);
}
__device__ inline float bf2f(short s) {
  __hip_bfloat16 b = *reinterpret_cast<__hip_bfloat16*>(&s);
  return __bfloat162float(b);
}

// exact round-1 score chain: sequential fmaf over d=0..63 (bit-identical to baseline)
__device__ float exact_dot(const float* Qr, const float* __restrict__ Kr) {
  float acc = 0.f;
  #pragma unroll
  for (int d4 = 0; d4 < 16; ++d4) {
    float4 a = ((const float4*)Qr)[d4];
    float4 b = ((const float4*)Kr)[d4];
    acc = fmaf(a.x, b.x, acc);
    acc = fmaf(a.y, b.y, acc);
    acc = fmaf(a.z, b.z, acc);
    acc = fmaf(a.w, b.w, acc);
  }
  return acc;
}

// ---------------- prep kernel: build bf16 planes in ws ----------------
// QW: per head [q][plane2][64]                       (plain)
// KW: per head [kt16:128][row16][plane2][blk8^ (row&7)][8]
// VW: per head [slab:32][d64][blk8 ^ (d&7)][8]       (V transposed: Vt[d][k])
__global__ __launch_bounds__(256) void prep_kernel(
    const float* __restrict__ Q, const float* __restrict__ K, const float* __restrict__ V,
    short* __restrict__ qw, short* __restrict__ kw, short* __restrict__ vw, int secblocks) {
  const int bid = blockIdx.x, tid = threadIdx.x;
  if (bid < secblocks) {               // ---- Q section ----
    int flat = bid * 256 + tid;        // (head, q, b) over heads*2048*8
    int head = flat >> 14;
    int rem = flat & 16383;
    int q = rem >> 3, b = rem & 7;
    const float* src = Q + (size_t)(head * S_LEN + q) * DK + b * 8;
    bf16x8 hv, mv;
    #pragma unroll
    for (int i = 0; i < 8; ++i) {
      float x = src[i];
      short h = f2bf(x);
      short m = f2bf(x - bf2f(h));
      hv[i] = h; mv[i] = m;
    }
    short* dst = qw + (size_t)(head * S_LEN + q) * 128;
    *(bf16x8*)(dst + 0 * 64 + b * 8) = hv;
    *(bf16x8*)(dst + 1 * 64 + b * 8) = mv;
  } else if (bid < 2 * secblocks) {    // ---- K section ----
    int flat = (bid - secblocks) * 256 + tid;   // (head, kt, row, b)
    int head = flat >> 14;
    int rem = flat & 16383;
    int kt = rem >> 7;
    int row = (rem >> 3) & 15, b = rem & 7;
    const float* src = K + (size_t)(head * S_LEN + kt * 16 + row) * DK + b * 8;
    bf16x8 hv, mv;
    #pragma unroll
    for (int i = 0; i < 8; ++i) {
      float x = src[i];
      short h = f2bf(x);
      short m = f2bf(x - bf2f(h));
      hv[i] = h; mv[i] = m;
    }
    int bs = b ^ (row & 7);
    short* dst = kw + ((size_t)(head * 128 + kt) * 16 + row) * 128;
    *(bf16x8*)(dst + 0 * 64 + bs * 8) = hv;
    *(bf16x8*)(dst + 1 * 64 + bs * 8) = mv;
  } else {                             // ---- V section (transpose) ----
    int wid = (bid - 2 * secblocks) * 4 + (tid >> 6);  // (head, slab, b) over heads*32*8
    int lane = tid & 63;               // = d
    int head = wid >> 8;
    int rem = wid & 255;
    int slab = rem >> 3, b = rem & 7;
    bf16x8 vv;
    #pragma unroll
    for (int j = 0; j < 8; ++j)
      vv[j] = f2bf(V[(size_t)(head * S_LEN + slab * 64 + b * 8 + j) * DK + lane]);
    int bs = b ^ (lane & 7);
    *(bf16x8*)(vw + ((size_t)(head * 32 + slab) * 64 + lane) * 64 + bs * 8) = vv;
  }
}

// ---------------- main kernel: zero-barrier, per-wave independent, XCD-clustered --------
__global__ __launch_bounds__(256, 3) void sdpa_mfma(
    const float* __restrict__ Q, const float* __restrict__ K,
    const short* __restrict__ qw, const short* __restrict__ kw, const short* __restrict__ vw,
    float* __restrict__ ctx_out, float* __restrict__ attn_out) {
  __shared__ short es[4][1024];     // per-wave [q16][k64] bf16, 16B-block swizzle ^ (q&7)
  __shared__ float att[4][1024];    // per-wave 4KB f32 attn bounce: [row16][blk16 ^ row][4]
  __shared__ float Qs[64][64];      // block's 64 q-rows fp32 (for exact_dot), 16KB

  // XCD-aware decode: b = (head%8) + 8*(qb + 32*(head/8)); XCD = b%8 = head%8 ->
  // all 32 q-blocks of a head share one XCD's L2 (2.4MB/XCD working set < 4MB).
  const int b = blockIdx.x;
  const int inner = b >> 3;
  const int qb = inner & (NQB - 1);
  const int head = (b & 7) + 8 * (inner >> 5);
  const int q0 = qb * MQ;
  const int tid = threadIdx.x;
  const int w = tid >> 6;
  const int lane = tid & 63;
  const int l15 = lane & 15;
  const int quad = lane >> 4;
  const int qrow = q0 + 16 * w + l15;    // this thread's q row (fixed for whole kernel)

  const short* QW = qw + (size_t)head * (S_LEN * 128);
  const short* KW = kw + (size_t)head * (128 * 16 * 128);
  const short* VW = vw + (size_t)head * (32 * 4096);
  const float* Qg = Q + (size_t)head * S_LEN * DK;
  const float* Kg = K + (size_t)head * S_LEN * DK;

  const f32x4 zf = {0.f, 0.f, 0.f, 0.f};

  // stage this block's Q fp32 rows into LDS (verbatim copy -> exact_dot bit-identical)
  #pragma unroll
  for (int i = 0; i < 4; ++i) {
    int idx = tid + 256 * i;            // float4 index over [64][16]
    ((float4*)Qs)[idx] = ((const float4*)(Qg + (size_t)q0 * DK))[idx];
  }

  // Q B-operand fragments for THIS wave's q-tile only. B[k=d][n=q]: n=l15 -> q = qrow;
  // k = c*32 + quad*8 + j.
  bf16x8 qf[2][2];   // [plane][chunk]
  #pragma unroll
  for (int p = 0; p < 2; ++p)
    #pragma unroll
    for (int c = 0; c < 2; ++c)
      qf[p][c] = *(const bf16x8*)(QW + (size_t)qrow * 128 + p * 64 + (c * 4 + quad) * 8);

  __syncthreads();   // Qs staged (only barrier in the kernel)

  // QK for one 64k x 16q slab: acc[kt]; C[m=k][n=q]: col=l15=q, row=quad*4+r = k-in-tile.
  // Same 6-MFMA chain order as the passing kernel -> bit-identical dots.
  #define QK_SLAB(acc, slabBase)                                                               \
    {                                                                                          \
      _Pragma("unroll")                                                                        \
      for (int kt = 0; kt < 4; ++kt) {                                                         \
        const short* kb = (slabBase) + ((size_t)kt * 16 + l15) * 128;                          \
        bf16x8 ak[2][2];                                                                       \
        _Pragma("unroll")                                                                      \
        for (int p = 0; p < 2; ++p)                                                            \
          _Pragma("unroll")                                                                    \
          for (int c = 0; c < 2; ++c)                                                          \
            ak[p][c] = *(const bf16x8*)(kb + p * 64 + (((c * 4 + quad) ^ (l15 & 7)) * 8));     \
        _Pragma("unroll")                                                                      \
        for (int c = 0; c < 2; ++c) {                                                          \
          acc[kt] = __builtin_amdgcn_mfma_f32_16x16x32_bf16(ak[0][c], qf[0][c], acc[kt], 0, 0, 0); \
          acc[kt] = __builtin_amdgcn_mfma_f32_16x16x32_bf16(ak[1][c], qf[0][c], acc[kt], 0, 0, 0); \
          acc[kt] = __builtin_amdgcn_mfma_f32_16x16x32_bf16(ak[0][c], qf[1][c], acc[kt], 0, 0, 0); \
        }                                                                                      \
      }                                                                                        \
    }

  // ================= pass A: Z (no LDS traffic, no barriers) =================
  float zsum = 0.f;
  #pragma unroll 2
  for (int step = 0; step < NSTEP; ++step) {
    const short* sb = KW + (size_t)step * 8192;
    f32x4 acc[4] = {zf, zf, zf, zf};
    QK_SLAB(acc, sb);
    #pragma unroll
    for (int kt = 0; kt < 4; ++kt)
      #pragma unroll
      for (int r = 0; r < 4; ++r) {
        float d = acc[kt][r];
        zsum += (d < 0.f) ? __expf(d * 0.125f) : 0.f;
      }
  }
  // quads hold disjoint k for the same q=l15 -> butterfly over lane bits 4,5
  zsum += __shfl_xor(zsum, 16);
  zsum += __shfl_xor(zsum, 32);
  const float zinv = 1.f / (zsum + 1e-8f);

  // ================= pass B: attn + PV (no barriers) =================
  f32x4 ctxa[4] = {zf, zf, zf, zf};   // ctx^T: [dt]; row d=dt*16+quad*4+r, col q=qrow
  short* esw = &es[w][0];             // this wave's private e tile (bf16)
  float* aw = &att[w][0];             // this wave's private attn bounce tile (f32)
  const float* Qlds = &Qs[16 * w + l15][0];   // this thread's q-row in LDS

  #pragma unroll 2
  for (int step = 0; step < NSTEP; ++step) {
    const short* sb = KW + (size_t)step * 8192;
    f32x4 acc[4] = {zf, zf, zf, zf};
    QK_SLAB(acc, sb);

    #pragma unroll
    for (int kt = 0; kt < 4; ++kt) {
      const int kbase = step * 64 + kt * 16 + quad * 4;
      float e4[4];
      #pragma unroll
      for (int r = 0; r < 4; ++r) {
        float d = acc[kt][r];
        if (fabsf(d) < DOT_EPS) {   // rare (~0.2%): exact sign via round-1 chain
          d = exact_dot(Qlds, Kg + (size_t)(kbase + r) * DK);
        }
        e4[r] = (d < 0.f) ? __expf(d * 0.125f) : 0.f;
      }
      // attn bounce write: row q=l15, 16B-block b = kt*4+quad, swizzled position b^l15.
      f32x4 av = {e4[0] * zinv, e4[1] * zinv, e4[2] * zinv, e4[3] * zinv};
      *(f32x4*)(aw + l15 * 64 + ((kt * 4 + quad) ^ l15) * 4) = av;
      // es write: row q=l15, cols kt*16+quad*4 .. +3; block b = kt*2+(quad>>1), swz ^ (q&7)
      int bb = kt * 2 + (quad >> 1);
      short* ep = esw + l15 * 64 + ((bb ^ (l15 & 7)) * 8) + (quad & 1) * 4;
      *(short4*)ep = make_short4(f2bf(e4[0]), f2bf(e4[1]), f2bf(e4[2]), f2bf(e4[3]));
    }

    // attn store: 4 instrs, each 4 rows x 256B CONTIGUOUS (full 128B lines only).
    // lane l -> row r = 4i + (l>>4), col-block l&15 (read swizzled position (l&15)^r).
    #pragma unroll
    for (int i = 0; i < 4; ++i) {
      const int r = 4 * i + quad;
      f32x4 rv = *(const f32x4*)(aw + r * 64 + (l15 ^ r) * 4);
      __builtin_nontemporal_store(rv,
          (f32x4*)(attn_out + (size_t)(head * S_LEN + q0 + 16 * w + r) * S_LEN +
                   step * 64 + l15 * 4));
    }

    // PV: ctx^T += V^T * e^T. Wave-synchronous LDS (ds in-order per wave; compiler
    // inserts the lgkmcnt wait for the es read data).
    bf16x8 eb[2];
    #pragma unroll
    for (int c = 0; c < 2; ++c)
      eb[c] = *(const bf16x8*)(esw + l15 * 64 + (((c * 4 + quad) ^ (l15 & 7)) * 8));
    #pragma unroll
    for (int dt = 0; dt < 4; ++dt) {
      const int d = dt * 16 + l15;   // A[m=d][k]
      #pragma unroll
      for (int c = 0; c < 2; ++c) {
        bf16x8 va = *(const bf16x8*)(VW + (size_t)step * 4096 + (size_t)d * 64 +
                                     (((c * 4 + quad) ^ (l15 & 7)) * 8));
        ctxa[dt] = __builtin_amdgcn_mfma_f32_16x16x32_bf16(va, eb[c], ctxa[dt], 0, 0, 0);
      }
    }
  }

  // ctx store: thread holds ctx^T[d=dt*16+quad*4+r][q=qrow]; all 16 values share q -> zinv.
  #pragma unroll
  for (int dt = 0; dt < 4; ++dt) {
    float4 cv = {ctxa[dt][0] * zinv, ctxa[dt][1] * zinv, ctxa[dt][2] * zinv, ctxa[dt][3] * zinv};
    *(float4*)(ctx_out + (size_t)(head * S_LEN + qrow) * DK + dt * 16 + quad * 4) = cv;
  }
}

extern "C" void kernel_launch(void* const* d_in, const int* in_sizes, int n_in,
                              void* d_out, int out_size, void* d_ws, size_t ws_size,
                              hipStream_t stream) {
  const float* Q = (const float*)d_in[0];
  const float* K = (const float*)d_in[1];
  const float* V = (const float*)d_in[2];
  const int heads = in_sizes[0] / (S_LEN * DK);   // 24

  float* ctx = (float*)d_out;
  float* attn = (float*)d_out + (size_t)heads * S_LEN * DK;

  short* qw = (short*)d_ws;                                  // heads*2048*128 bf16
  short* kw = qw + (size_t)heads * S_LEN * 128;              // heads*128*16*128
  short* vw = kw + (size_t)heads * 128 * 16 * 128;           // heads*32*4096

  const int secblocks = heads * 64;                          // blocks per prep section
  prep_kernel<<<dim3(3 * secblocks), dim3(256), 0, stream>>>(Q, K, V, qw, kw, vw, secblocks);
  sdpa_mfma<<<dim3(NQB * heads), dim3(256), 0, stream>>>(Q, K, qw, kw, vw, ctx, attn);
}